// Round 6
// baseline (245.419 us; speedup 1.0000x reference)
//
#include <hip/hip_runtime.h>
#include <hip/hip_bf16.h>
#include <hip/hip_fp16.h>

#define NTOK 8192
#define DDIM 1024
#define HDIM 1024
#define NEXP 8

typedef __attribute__((ext_vector_type(8))) short short8;
typedef __attribute__((ext_vector_type(4))) float f32x4;
typedef __attribute__((ext_vector_type(4))) unsigned short us4;
typedef __attribute__((ext_vector_type(8))) unsigned short us8;

static __device__ __forceinline__ unsigned short f2bf(float f) {
  union { float f; unsigned u; } v; v.f = f;
  return (unsigned short)((v.u + 0x7fffu + ((v.u >> 16) & 1u)) >> 16);
}

static __device__ __forceinline__ void gload16(const void* g, void* l) {
  __builtin_amdgcn_global_load_lds(
      (const __attribute__((address_space(1))) unsigned int*)g,
      (__attribute__((address_space(3))) unsigned int*)l, 16, 0, 0);
}

// ---------------- Wg [D][E] -> WgT [E][D] (32 KB, trivial) --------------------------
__global__ __launch_bounds__(256) void wg_transpose(
    const float* __restrict__ Wg, float* __restrict__ wgT)
{
  const int i = blockIdx.x * 256 + threadIdx.x;   // 8192
  const int e = i >> 10, d = i & 1023;
  wgT[i] = Wg[d * NEXP + e];
}

// ---------------- gate: fp32 logits via WgT (coalesced), top-2, fused x->bf16 -------
__global__ __launch_bounds__(256) void gate_kernel(
    const float* __restrict__ x, const float* __restrict__ wgT,
    const float* __restrict__ bg, unsigned short* __restrict__ xb,
    int* __restrict__ sel, float* __restrict__ wts)
{
  const int token = blockIdx.x * 4 + (threadIdx.x >> 6);
  const int lane = threadIdx.x & 63;
  const float* xr = x + (size_t)token * DDIM;

  float acc[NEXP];
#pragma unroll
  for (int e = 0; e < NEXP; ++e) acc[e] = 0.f;

#pragma unroll
  for (int q = 0; q < 4; ++q) {
    const int d0 = q * 256 + lane * 4;
    const float4 xv = *(const float4*)(xr + d0);
    us4 hb;
    hb.x = f2bf(xv.x); hb.y = f2bf(xv.y); hb.z = f2bf(xv.z); hb.w = f2bf(xv.w);
    *(us4*)(xb + (size_t)token * DDIM + d0) = hb;
#pragma unroll
    for (int e = 0; e < NEXP; ++e) {
      const float4 wv = *(const float4*)(wgT + e * DDIM + d0);
      acc[e] += xv.x * wv.x;   // j=0..3 order matches previous passing kernel
      acc[e] += xv.y * wv.y;
      acc[e] += xv.z * wv.z;
      acc[e] += xv.w * wv.w;
    }
  }

#pragma unroll
  for (int e = 0; e < NEXP; ++e) {
#pragma unroll
    for (int off = 32; off >= 1; off >>= 1)
      acc[e] += __shfl_xor(acc[e], off, 64);
  }

  if (lane == 0) {
    float v[NEXP];
#pragma unroll
    for (int e = 0; e < NEXP; ++e) v[e] = acc[e] + bg[e];
    int i0 = 0; float v0 = v[0];
#pragma unroll
    for (int e = 1; e < NEXP; ++e) if (v[e] > v0) { v0 = v[e]; i0 = e; }
    int i1 = -1; float v1 = -3.4e38f;
#pragma unroll
    for (int e = 0; e < NEXP; ++e) if (e != i0 && v[e] > v1) { v1 = v[e]; i1 = e; }
    const float t = __expf(v1 - v0);
    const float w0 = 1.f / (1.f + t);
    const float w1 = t / (1.f + t);
    sel[token * 2 + 0] = i0;  wts[token * 2 + 0] = w0;
    sel[token * 2 + 1] = i1;  wts[token * 2 + 1] = w1;
  }
}

// ---------------- route: block-aggregated scatter into per-expert lists -------------
__global__ __launch_bounds__(256) void route_kernel(
    const int* __restrict__ sel, const float* __restrict__ wts,
    int* __restrict__ counts, int* __restrict__ tlist, float* __restrict__ wlist,
    int* __restrict__ dstrow)
{
  __shared__ int bin[NEXP];
  __shared__ int base[NEXP];
  const int tid = threadIdx.x;
  if (tid < NEXP) bin[tid] = 0;
  __syncthreads();
  const int idx = blockIdx.x * 256 + tid;
  const int e = sel[idx];
  const float w = wts[idx];
  const int rank = atomicAdd(&bin[e], 1);
  __syncthreads();
  if (tid < NEXP) base[tid] = atomicAdd(&counts[tid], bin[tid]);
  __syncthreads();
  const int pos = base[e] + rank;
  tlist[e * NTOK + pos] = idx >> 1;
  wlist[e * NTOK + pos] = w;
  dstrow[e * NTOK + pos] = idx;
}

// ------- We [E][D][H] fp32 -> [E][H][D] bf16; 128d x 64h tiles, 256B segments -------
__global__ __launch_bounds__(256) void transpose_we(
    const float* __restrict__ We, unsigned short* __restrict__ wbt)
{
  const int e = blockIdx.z;
  const int h0 = blockIdx.x * 64;
  const int d0 = blockIdx.y * 128;
  __shared__ float t[128][65];
  const int tx = threadIdx.x;

  {
    const int hc = (tx & 15) * 4;
    const float* src = We + ((size_t)e * DDIM + d0) * HDIM + h0 + hc;
#pragma unroll
    for (int i = 0; i < 8; ++i) {
      const int dr = (tx >> 4) + i * 16;
      const float4 v = *(const float4*)(src + (size_t)dr * HDIM);
      t[dr][hc] = v.x; t[dr][hc + 1] = v.y; t[dr][hc + 2] = v.z; t[dr][hc + 3] = v.w;
    }
  }
  __syncthreads();
  {
    const int dc = (tx & 7) * 16;
#pragma unroll
    for (int i2 = 0; i2 < 2; ++i2) {
      const int hr = (tx >> 3) + i2 * 32;
      us8 o0, o1;
#pragma unroll
      for (int j = 0; j < 8; ++j) ((unsigned short*)&o0)[j] = f2bf(t[dc + j][hr]);
#pragma unroll
      for (int j = 0; j < 8; ++j) ((unsigned short*)&o1)[j] = f2bf(t[dc + 8 + j][hr]);
      unsigned short* dst = wbt + ((size_t)e * HDIM + h0 + hr) * DDIM + d0 + dc;
      *(us8*)dst = o0;
      *(us8*)(dst + 8) = o1;
    }
  }
}

// -- grouped GEMM: 256x256, BK=64, 8 waves (2m x 4n), DOUBLE-BUFFERED LDS (2-phase) --
__global__ __launch_bounds__(512, 2) void moe_gemm(
    const unsigned short* __restrict__ xb,
    const unsigned short* __restrict__ wbt,
    const float* __restrict__ be,
    const int* __restrict__ counts,
    const int* __restrict__ tlist,
    const float* __restrict__ wlist,
    const int* __restrict__ dstrow,
    __half* __restrict__ yb)
{
  const int e = blockIdx.z;
  const int cnt = counts[e];
  const int tile = blockIdx.y;
  if (tile * 256 >= cnt) return;
  const int n0 = blockIdx.x * 256;

  __shared__ unsigned short As[2][256 * 64];   // 2 x 32 KB
  __shared__ unsigned short Bs[2][256 * 64];   // 2 x 32 KB  (128 KB total, m201 size)

  const int tid = threadIdx.x;              // 0..511
  const int lane = tid & 63;
  const int wv = tid >> 6;                  // 0..7
  const int wm = wv >> 2;                   // 0..1  (m position, 128 rows each)
  const int wn = wv & 3;                    // 0..3  (n position, 64 cols each)

  // staging: row r (128B), 16B chunk (tid&7); swizzled SOURCE + linear LDS (rule 21)
  const int rA = tid >> 3;                  // 0..63
  const int kbA = (tid & 7) << 4;
  int aOff[4]; int bOff[4]; int ldsO[4];
#pragma unroll
  for (int q = 0; q < 4; ++q) {
    const int r = q * 64 + rA;              // 0..255
    int trow = tile * 256 + r;
    trow = trow < cnt ? trow : cnt - 1;
    const int tok = tlist[e * NTOK + trow];
    const int kbs = kbA ^ ((r & 7) << 4);
    aOff[q] = tok * DDIM + (kbs >> 1);
    bOff[q] = (e * HDIM + n0 + r) * DDIM + (kbs >> 1);
    ldsO[q] = r * 64 + (kbA >> 1);
  }

  f32x4 acc[8][4];
#pragma unroll
  for (int m = 0; m < 8; ++m)
#pragma unroll
    for (int n = 0; n < 4; ++n)
      acc[m][n] = (f32x4){0.f, 0.f, 0.f, 0.f};

  // prologue: stage K-tile 0 into buffer 0
#pragma unroll
  for (int q = 0; q < 4; ++q) gload16(xb + aOff[q], &As[0][ldsO[q]]);
#pragma unroll
  for (int q = 0; q < 4; ++q) gload16(wbt + bOff[q], &Bs[0][ldsO[q]]);
  asm volatile("s_waitcnt vmcnt(0)" ::: "memory");
  __syncthreads();

#pragma unroll 2
  for (int kt = 0; kt < DDIM / 64; ++kt) {
    const int cur = kt & 1;
    const int nxt = cur ^ 1;
    // issue next tile's staging FIRST (overlaps with this tile's MFMA)
    if (kt < DDIM / 64 - 1) {
#pragma unroll
      for (int q = 0; q < 4; ++q) gload16(xb + aOff[q] + (kt + 1) * 64, &As[nxt][ldsO[q]]);
#pragma unroll
      for (int q = 0; q < 4; ++q) gload16(wbt + bOff[q] + (kt + 1) * 64, &Bs[nxt][ldsO[q]]);
    }
    // compute current tile
#pragma unroll
    for (int kk = 0; kk < 2; ++kk) {
      const int kb = kk * 64 + ((lane >> 4) << 4);
      short8 af[8], bfr[4];
#pragma unroll
      for (int m = 0; m < 8; ++m) {
        const int r = wm * 128 + m * 16 + (lane & 15);
        af[m] = *(const short8*)((const char*)(&As[cur][0]) + r * 128 + (kb ^ ((r & 7) << 4)));
      }
#pragma unroll
      for (int n = 0; n < 4; ++n) {
        const int r = wn * 64 + n * 16 + (lane & 15);
        bfr[n] = *(const short8*)((const char*)(&Bs[cur][0]) + r * 128 + (kb ^ ((r & 7) << 4)));
      }
      __builtin_amdgcn_s_setprio(1);
#pragma unroll
      for (int m = 0; m < 8; ++m)
#pragma unroll
        for (int n = 0; n < 4; ++n)
          acc[m][n] = __builtin_amdgcn_mfma_f32_16x16x32_bf16(af[m], bfr[n], acc[m][n], 0, 0, 0);
      __builtin_amdgcn_s_setprio(0);
    }
    asm volatile("s_waitcnt vmcnt(0)" ::: "memory");
    __syncthreads();
  }

  // epilogue: yb[dstrow][h] = w * (acc + be[e][h])  (plain fp16 stores, no atomics)
  const int rbase = wm * 128 + ((lane >> 4) << 2);
  const int cb = lane & 15;
  float bev[4];
#pragma unroll
  for (int n = 0; n < 4; ++n) bev[n] = be[e * HDIM + n0 + wn * 64 + n * 16 + cb];
#pragma unroll
  for (int m = 0; m < 8; ++m) {
#pragma unroll
    for (int r4 = 0; r4 < 4; ++r4) {
      const int trow = tile * 256 + rbase + m * 16 + r4;
      if (trow < cnt) {
        const int drow = dstrow[e * NTOK + trow];
        const float w = wlist[e * NTOK + trow];
        __half* yrow = yb + (size_t)drow * HDIM + n0 + wn * 64 + cb;
#pragma unroll
        for (int n = 0; n < 4; ++n)
          yrow[n * 16] = __float2half(w * (acc[m][n][r4] + bev[n]));
      }
    }
  }
}

// ---------------- combine: out[tok] = partial[tok*2] + partial[tok*2+1] -------------
__global__ __launch_bounds__(256) void combine_kernel(
    const __half* __restrict__ yb, float* __restrict__ out)
{
  const int g = blockIdx.x * 256 + threadIdx.x;
  const int tok = g >> 7;
  const int h0 = (g & 127) * 8;
  const short8 p0 = *(const short8*)(yb + ((size_t)tok * 2) * HDIM + h0);
  const short8 p1 = *(const short8*)(yb + ((size_t)tok * 2 + 1) * HDIM + h0);
  float r[8];
#pragma unroll
  for (int j = 0; j < 8; ++j) {
    __half a = *(const __half*)&((const short*)&p0)[j];
    __half b = *(const __half*)&((const short*)&p1)[j];
    r[j] = __half2float(a) + __half2float(b);
  }
  float* o = out + (size_t)tok * HDIM + h0;
  *(float4*)o = (float4){r[0], r[1], r[2], r[3]};
  *(float4*)(o + 4) = (float4){r[4], r[5], r[6], r[7]};
}

extern "C" void kernel_launch(void* const* d_in, const int* in_sizes, int n_in,
                              void* d_out, int out_size, void* d_ws, size_t ws_size,
                              hipStream_t stream)
{
  const float* x  = (const float*)d_in[0];
  const float* Wg = (const float*)d_in[1];
  const float* bg = (const float*)d_in[2];
  const float* We = (const float*)d_in[3];
  const float* be = (const float*)d_in[4];

  char* ws = (char*)d_ws;
  int*   counts = (int*)ws;                                   // 256 B
  int*   tlist  = (int*)(ws + 256);                           // 256 KB
  float* wlist  = (float*)(ws + 256 + NEXP * NTOK * 4);       // 256 KB
  int*   dstrow = (int*)(ws + 256 + 2 * NEXP * NTOK * 4);     // 256 KB
  int*   sel    = (int*)(ws + 256 + 3 * NEXP * NTOK * 4);     // 64 KB
  float* wts    = (float*)(ws + 256 + 3 * NEXP * NTOK * 4 + 2 * NTOK * 4); // 64 KB
  float* wgT    = (float*)(ws + 0x180000);                    // 32 KB @ 1.5 MB
  unsigned short* xb  = (unsigned short*)(ws + (1 << 21));                           // 16 MB
  unsigned short* wbt = (unsigned short*)(ws + (1 << 21) + (size_t)NTOK * DDIM * 2); // 16 MB
  __half* yb = (__half*)(ws + (1 << 21) + 2 * (size_t)NTOK * DDIM * 2);              // 32 MB
  float* out = (float*)d_out;

  hipMemsetAsync(counts, 0, 256, stream);

  wg_transpose<<<32, 256, 0, stream>>>(Wg, wgT);
  gate_kernel<<<NTOK / 4, 256, 0, stream>>>(x, wgT, bg, xb, sel, wts);
  route_kernel<<<2 * NTOK / 256, 256, 0, stream>>>(sel, wts, counts, tlist, wlist, dstrow);
  transpose_we<<<dim3(HDIM / 64, DDIM / 128, NEXP), 256, 0, stream>>>(We, wbt);
  moe_gemm<<<dim3(HDIM / 256, NTOK / 256, NEXP), 512, 0, stream>>>(
      xb, wbt, be, counts, tlist, wlist, dstrow, yb);
  combine_kernel<<<NTOK * HDIM / 8 / 256, 256, 0, stream>>>(yb, out);
}

// Round 7
// 201.462 us; speedup vs baseline: 1.2182x; 1.2182x over previous
//
#include <hip/hip_runtime.h>
#include <hip/hip_bf16.h>
#include <hip/hip_fp16.h>

#define NTOK 8192
#define DDIM 1024
#define HDIM 1024
#define NEXP 8

typedef __attribute__((ext_vector_type(8))) short short8;
typedef __attribute__((ext_vector_type(4))) float f32x4;
typedef __attribute__((ext_vector_type(4))) unsigned short us4;
typedef __attribute__((ext_vector_type(8))) unsigned short us8;

static __device__ __forceinline__ unsigned short f2bf(float f) {
  union { float f; unsigned u; } v; v.f = f;
  return (unsigned short)((v.u + 0x7fffu + ((v.u >> 16) & 1u)) >> 16);
}

static __device__ __forceinline__ void gload16(const void* g, void* l) {
  __builtin_amdgcn_global_load_lds(
      (const __attribute__((address_space(1))) unsigned int*)g,
      (__attribute__((address_space(3))) unsigned int*)l, 16, 0, 0);
}

// ---------------- Wg [D][E] -> WgT [E][D] (32 KB, trivial) --------------------------
__global__ __launch_bounds__(256) void wg_transpose(
    const float* __restrict__ Wg, float* __restrict__ wgT)
{
  const int i = blockIdx.x * 256 + threadIdx.x;   // 8192
  const int e = i >> 10, d = i & 1023;
  wgT[i] = Wg[d * NEXP + e];
}

// -------- gate v3: wgT staged in LDS, 16 tokens/block, fp32 top-2, fused x->bf16 ----
__global__ __launch_bounds__(256) void gate_kernel(
    const float* __restrict__ x, const float* __restrict__ wgT,
    const float* __restrict__ bg, unsigned short* __restrict__ xb,
    int* __restrict__ sel, float* __restrict__ wts)
{
  __shared__ float wg[NEXP * DDIM];   // 32 KB
  const int tid = threadIdx.x;
#pragma unroll
  for (int i = 0; i < 8; ++i) {
    const int o = (i * 256 + tid) * 4;
    *(float4*)&wg[o] = *(const float4*)&wgT[o];
  }
  __syncthreads();

  const int wave = tid >> 6;
  const int lane = tid & 63;

  for (int t = 0; t < 4; ++t) {
    const int token = blockIdx.x * 16 + wave * 4 + t;
    const float* xr = x + (size_t)token * DDIM;

    float acc[NEXP];
#pragma unroll
    for (int e = 0; e < NEXP; ++e) acc[e] = 0.f;

#pragma unroll
    for (int q = 0; q < 4; ++q) {
      const int d0 = q * 256 + lane * 4;
      const float4 xv = *(const float4*)(xr + d0);
      us4 hb;
      hb.x = f2bf(xv.x); hb.y = f2bf(xv.y); hb.z = f2bf(xv.z); hb.w = f2bf(xv.w);
      *(us4*)(xb + (size_t)token * DDIM + d0) = hb;
#pragma unroll
      for (int e = 0; e < NEXP; ++e) {
        const float4 wv = *(const float4*)&wg[e * DDIM + d0];
        acc[e] += xv.x * wv.x;   // same j-order as previous passing kernels
        acc[e] += xv.y * wv.y;
        acc[e] += xv.z * wv.z;
        acc[e] += xv.w * wv.w;
      }
    }

#pragma unroll
    for (int e = 0; e < NEXP; ++e) {
#pragma unroll
      for (int off = 32; off >= 1; off >>= 1)
        acc[e] += __shfl_xor(acc[e], off, 64);
    }

    if (lane == 0) {
      float v[NEXP];
#pragma unroll
      for (int e = 0; e < NEXP; ++e) v[e] = acc[e] + bg[e];
      int i0 = 0; float v0 = v[0];
#pragma unroll
      for (int e = 1; e < NEXP; ++e) if (v[e] > v0) { v0 = v[e]; i0 = e; }
      int i1 = -1; float v1 = -3.4e38f;
#pragma unroll
      for (int e = 0; e < NEXP; ++e) if (e != i0 && v[e] > v1) { v1 = v[e]; i1 = e; }
      const float tt = __expf(v1 - v0);
      const float w0 = 1.f / (1.f + tt);
      const float w1 = tt / (1.f + tt);
      sel[token * 2 + 0] = i0;  wts[token * 2 + 0] = w0;
      sel[token * 2 + 1] = i1;  wts[token * 2 + 1] = w1;
    }
  }
}

// ---------------- route: block-aggregated scatter into per-expert lists -------------
__global__ __launch_bounds__(256) void route_kernel(
    const int* __restrict__ sel, const float* __restrict__ wts,
    int* __restrict__ counts, int* __restrict__ tlist, float* __restrict__ wlist,
    int* __restrict__ dstrow)
{
  __shared__ int bin[NEXP];
  __shared__ int base[NEXP];
  const int tid = threadIdx.x;
  if (tid < NEXP) bin[tid] = 0;
  __syncthreads();
  const int idx = blockIdx.x * 256 + tid;
  const int e = sel[idx];
  const float w = wts[idx];
  const int rank = atomicAdd(&bin[e], 1);
  __syncthreads();
  if (tid < NEXP) base[tid] = atomicAdd(&counts[tid], bin[tid]);
  __syncthreads();
  const int pos = base[e] + rank;
  tlist[e * NTOK + pos] = idx >> 1;
  wlist[e * NTOK + pos] = w;
  dstrow[e * NTOK + pos] = idx;
}

// ------- We [E][D][H] fp32 -> [E][H][D] bf16; 128d x 64h tiles, 256B segments -------
__global__ __launch_bounds__(256) void transpose_we(
    const float* __restrict__ We, unsigned short* __restrict__ wbt)
{
  const int e = blockIdx.z;
  const int h0 = blockIdx.x * 64;
  const int d0 = blockIdx.y * 128;
  __shared__ float t[128][65];
  const int tx = threadIdx.x;

  {
    const int hc = (tx & 15) * 4;
    const float* src = We + ((size_t)e * DDIM + d0) * HDIM + h0 + hc;
#pragma unroll
    for (int i = 0; i < 8; ++i) {
      const int dr = (tx >> 4) + i * 16;
      const float4 v = *(const float4*)(src + (size_t)dr * HDIM);
      t[dr][hc] = v.x; t[dr][hc + 1] = v.y; t[dr][hc + 2] = v.z; t[dr][hc + 3] = v.w;
    }
  }
  __syncthreads();
  {
    const int dc = (tx & 7) * 16;
#pragma unroll
    for (int i2 = 0; i2 < 2; ++i2) {
      const int hr = (tx >> 3) + i2 * 32;
      us8 o0, o1;
#pragma unroll
      for (int j = 0; j < 8; ++j) ((unsigned short*)&o0)[j] = f2bf(t[dc + j][hr]);
#pragma unroll
      for (int j = 0; j < 8; ++j) ((unsigned short*)&o1)[j] = f2bf(t[dc + 8 + j][hr]);
      unsigned short* dst = wbt + ((size_t)e * HDIM + h0 + hr) * DDIM + d0 + dc;
      *(us8*)dst = o0;
      *(us8*)(dst + 8) = o1;
    }
  }
}

// ------- grouped GEMM (R3-verbatim): 256x128 tile, BK=64, 8 waves, fp16 partials ----
__global__ __launch_bounds__(512, 4) void moe_gemm(
    const unsigned short* __restrict__ xb,
    const unsigned short* __restrict__ wbt,
    const float* __restrict__ be,
    const int* __restrict__ counts,
    const int* __restrict__ tlist,
    const float* __restrict__ wlist,
    const int* __restrict__ dstrow,
    __half* __restrict__ yb)
{
  const int e = blockIdx.z;
  const int cnt = counts[e];
  const int tile = blockIdx.y;
  if (tile * 256 >= cnt) return;
  const int n0 = blockIdx.x * 128;

  __shared__ unsigned short As[256 * 64];   // 32 KB
  __shared__ unsigned short Bs[128 * 64];   // 16 KB

  const int tid = threadIdx.x;              // 0..511
  const int lane = tid & 63;
  const int wv = tid >> 6;                  // 0..7
  const int wm = wv >> 1;                   // 0..3  (m position, 64 rows each)
  const int wn = wv & 1;                    // 0..1  (n position, 64 cols each)

  // staging: row r (128B), 16B chunk (tid&7); swizzled SOURCE + linear LDS (rule 21)
  const int rA = tid >> 3;                  // 0..63
  const int kbA = (tid & 7) << 4;
  const unsigned short* aSrc[4];
  const unsigned short* bSrc[2];
  int ldsA[4]; int ldsB[2];
#pragma unroll
  for (int q = 0; q < 4; ++q) {
    const int r = q * 64 + rA;              // 0..255
    int trow = tile * 256 + r;
    trow = trow < cnt ? trow : cnt - 1;
    const int tok = tlist[e * NTOK + trow];
    const int kbs = kbA ^ ((r & 7) << 4);
    aSrc[q] = xb + (size_t)tok * DDIM + (kbs >> 1);
    ldsA[q] = r * 64 + (kbA >> 1);
  }
#pragma unroll
  for (int q = 0; q < 2; ++q) {
    const int r = q * 64 + rA;              // 0..127
    const int kbs = kbA ^ ((r & 7) << 4);
    bSrc[q] = wbt + ((size_t)e * HDIM + n0 + r) * DDIM + (kbs >> 1);
    ldsB[q] = r * 64 + (kbA >> 1);
  }

  f32x4 acc[4][4];
#pragma unroll
  for (int m = 0; m < 4; ++m)
#pragma unroll
    for (int n = 0; n < 4; ++n)
      acc[m][n] = (f32x4){0.f, 0.f, 0.f, 0.f};

  for (int kt = 0; kt < DDIM / 64; ++kt) {
    __syncthreads();
#pragma unroll
    for (int q = 0; q < 4; ++q) gload16(aSrc[q] + kt * 64, &As[ldsA[q]]);
#pragma unroll
    for (int q = 0; q < 2; ++q) gload16(bSrc[q] + kt * 64, &Bs[ldsB[q]]);
    __syncthreads();

#pragma unroll
    for (int kk = 0; kk < 2; ++kk) {
      const int kb = kk * 64 + ((lane >> 4) << 4);
      short8 af[4], bfr[4];
#pragma unroll
      for (int m = 0; m < 4; ++m) {
        const int r = wm * 64 + m * 16 + (lane & 15);
        af[m] = *(const short8*)((const char*)As + r * 128 + (kb ^ ((r & 7) << 4)));
      }
#pragma unroll
      for (int n = 0; n < 4; ++n) {
        const int r = wn * 64 + n * 16 + (lane & 15);
        bfr[n] = *(const short8*)((const char*)Bs + r * 128 + (kb ^ ((r & 7) << 4)));
      }
#pragma unroll
      for (int m = 0; m < 4; ++m)
#pragma unroll
        for (int n = 0; n < 4; ++n)
          acc[m][n] = __builtin_amdgcn_mfma_f32_16x16x32_bf16(af[m], bfr[n], acc[m][n], 0, 0, 0);
    }
  }

  // epilogue: yb[dstrow][h] = w * (acc + be[e][h])  (plain fp16 stores, no atomics)
  const int rbase = wm * 64 + ((lane >> 4) << 2);
  const int cb = lane & 15;
  float bev[4];
#pragma unroll
  for (int n = 0; n < 4; ++n) bev[n] = be[e * HDIM + n0 + wn * 64 + n * 16 + cb];
#pragma unroll
  for (int m = 0; m < 4; ++m) {
#pragma unroll
    for (int r4 = 0; r4 < 4; ++r4) {
      const int trow = tile * 256 + rbase + m * 16 + r4;
      if (trow < cnt) {
        const int drow = dstrow[e * NTOK + trow];
        const float w = wlist[e * NTOK + trow];
        __half* yrow = yb + (size_t)drow * HDIM + n0 + wn * 64 + cb;
#pragma unroll
        for (int n = 0; n < 4; ++n)
          yrow[n * 16] = __float2half(w * (acc[m][n][r4] + bev[n]));
      }
    }
  }
}

// ---------------- combine: out[tok] = partial[tok*2] + partial[tok*2+1] -------------
__global__ __launch_bounds__(256) void combine_kernel(
    const __half* __restrict__ yb, float* __restrict__ out)
{
  const int g = blockIdx.x * 256 + threadIdx.x;
  const int tok = g >> 7;
  const int h0 = (g & 127) * 8;
  const short8 p0 = *(const short8*)(yb + ((size_t)tok * 2) * HDIM + h0);
  const short8 p1 = *(const short8*)(yb + ((size_t)tok * 2 + 1) * HDIM + h0);
  float r[8];
#pragma unroll
  for (int j = 0; j < 8; ++j) {
    __half a = *(const __half*)&((const short*)&p0)[j];
    __half b = *(const __half*)&((const short*)&p1)[j];
    r[j] = __half2float(a) + __half2float(b);
  }
  float* o = out + (size_t)tok * HDIM + h0;
  *(float4*)o = (float4){r[0], r[1], r[2], r[3]};
  *(float4*)(o + 4) = (float4){r[4], r[5], r[6], r[7]};
}

extern "C" void kernel_launch(void* const* d_in, const int* in_sizes, int n_in,
                              void* d_out, int out_size, void* d_ws, size_t ws_size,
                              hipStream_t stream)
{
  const float* x  = (const float*)d_in[0];
  const float* Wg = (const float*)d_in[1];
  const float* bg = (const float*)d_in[2];
  const float* We = (const float*)d_in[3];
  const float* be = (const float*)d_in[4];

  char* ws = (char*)d_ws;
  int*   counts = (int*)ws;                                   // 256 B
  int*   tlist  = (int*)(ws + 256);                           // 256 KB
  float* wlist  = (float*)(ws + 256 + NEXP * NTOK * 4);       // 256 KB
  int*   dstrow = (int*)(ws + 256 + 2 * NEXP * NTOK * 4);     // 256 KB
  int*   sel    = (int*)(ws + 256 + 3 * NEXP * NTOK * 4);     // 64 KB
  float* wts    = (float*)(ws + 256 + 3 * NEXP * NTOK * 4 + 2 * NTOK * 4); // 64 KB
  float* wgT    = (float*)(ws + 0x180000);                    // 32 KB @ 1.5 MB
  unsigned short* xb  = (unsigned short*)(ws + (1 << 21));                           // 16 MB
  unsigned short* wbt = (unsigned short*)(ws + (1 << 21) + (size_t)NTOK * DDIM * 2); // 16 MB
  __half* yb = (__half*)(ws + (1 << 21) + 2 * (size_t)NTOK * DDIM * 2);              // 32 MB
  float* out = (float*)d_out;

  hipMemsetAsync(counts, 0, 256, stream);

  wg_transpose<<<32, 256, 0, stream>>>(Wg, wgT);
  gate_kernel<<<NTOK / 16, 256, 0, stream>>>(x, wgT, bg, xb, sel, wts);
  route_kernel<<<2 * NTOK / 256, 256, 0, stream>>>(sel, wts, counts, tlist, wlist, dstrow);
  transpose_we<<<dim3(HDIM / 64, DDIM / 128, NEXP), 256, 0, stream>>>(We, wbt);
  moe_gemm<<<dim3(HDIM / 128, NTOK / 256, NEXP), 512, 0, stream>>>(
      xb, wbt, be, counts, tlist, wlist, dstrow, yb);
  combine_kernel<<<NTOK * HDIM / 8 / 256, 256, 0, stream>>>(yb, out);
}

// Round 8
// 198.711 us; speedup vs baseline: 1.2351x; 1.0138x over previous
//
#include <hip/hip_runtime.h>
#include <hip/hip_bf16.h>
#include <hip/hip_fp16.h>

#define NTOK 8192
#define DDIM 1024
#define HDIM 1024
#define NEXP 8

typedef __attribute__((ext_vector_type(8))) short short8;
typedef __attribute__((ext_vector_type(4))) float f32x4;
typedef __attribute__((ext_vector_type(4))) unsigned short us4;
typedef __attribute__((ext_vector_type(8))) unsigned short us8;

static __device__ __forceinline__ unsigned short f2bf(float f) {
  union { float f; unsigned u; } v; v.f = f;
  return (unsigned short)((v.u + 0x7fffu + ((v.u >> 16) & 1u)) >> 16);
}

static __device__ __forceinline__ void gload16(const void* g, void* l) {
  __builtin_amdgcn_global_load_lds(
      (const __attribute__((address_space(1))) unsigned int*)g,
      (__attribute__((address_space(3))) unsigned int*)l, 16, 0, 0);
}

// ==== prep: blocks [0,512) = gate (Wg transposed in-LDS); [512,1536) = We-transpose;
//      block 512 additionally zeroes counts. All parts independent; consumers are in
//      later stream-ordered nodes. ====
__global__ __launch_bounds__(256) void prep_kernel(
    const float* __restrict__ x, const float* __restrict__ Wg,
    const float* __restrict__ bg, unsigned short* __restrict__ xb,
    int* __restrict__ sel, float* __restrict__ wts,
    const float* __restrict__ We, unsigned short* __restrict__ wbt,
    int* __restrict__ counts)
{
  __shared__ float smem[128 * 65];   // 33280 B, shared by both branches
  const int bi = blockIdx.x;
  const int tid = threadIdx.x;

  if (bi < NTOK / 16) {
    // ---------------- gate part: 16 tokens/block ----------------
    float* wg = smem;                // [NEXP][DDIM], 32 KB
    // stage Wg [D][E] -> wg [E][D]; lane reads 32B contiguous, LDS writes bank=tid&31
#pragma unroll
    for (int k = 0; k < 4; ++k) {
      const int d = tid + k * 256;
      const float4 a = *(const float4*)(Wg + d * NEXP);
      const float4 b = *(const float4*)(Wg + d * NEXP + 4);
      wg[0 * DDIM + d] = a.x; wg[1 * DDIM + d] = a.y;
      wg[2 * DDIM + d] = a.z; wg[3 * DDIM + d] = a.w;
      wg[4 * DDIM + d] = b.x; wg[5 * DDIM + d] = b.y;
      wg[6 * DDIM + d] = b.z; wg[7 * DDIM + d] = b.w;
    }
    __syncthreads();

    const int wave = tid >> 6;
    const int lane = tid & 63;

    for (int t = 0; t < 4; ++t) {
      const int token = bi * 16 + wave * 4 + t;
      const float* xr = x + (size_t)token * DDIM;

      float acc[NEXP];
#pragma unroll
      for (int e = 0; e < NEXP; ++e) acc[e] = 0.f;

#pragma unroll
      for (int q = 0; q < 4; ++q) {
        const int d0 = q * 256 + lane * 4;
        const float4 xv = *(const float4*)(xr + d0);
        us4 hb;
        hb.x = f2bf(xv.x); hb.y = f2bf(xv.y); hb.z = f2bf(xv.z); hb.w = f2bf(xv.w);
        *(us4*)(xb + (size_t)token * DDIM + d0) = hb;
#pragma unroll
        for (int e = 0; e < NEXP; ++e) {
          const float4 wv = *(const float4*)&wg[e * DDIM + d0];
          acc[e] += xv.x * wv.x;   // same j-order as all previous passing kernels
          acc[e] += xv.y * wv.y;
          acc[e] += xv.z * wv.z;
          acc[e] += xv.w * wv.w;
        }
      }

#pragma unroll
      for (int e = 0; e < NEXP; ++e) {
#pragma unroll
        for (int off = 32; off >= 1; off >>= 1)
          acc[e] += __shfl_xor(acc[e], off, 64);
      }

      if (lane == 0) {
        float v[NEXP];
#pragma unroll
        for (int e = 0; e < NEXP; ++e) v[e] = acc[e] + bg[e];
        int i0 = 0; float v0 = v[0];
#pragma unroll
        for (int e = 1; e < NEXP; ++e) if (v[e] > v0) { v0 = v[e]; i0 = e; }
        int i1 = -1; float v1 = -3.4e38f;
#pragma unroll
        for (int e = 0; e < NEXP; ++e) if (e != i0 && v[e] > v1) { v1 = v[e]; i1 = e; }
        const float tt = __expf(v1 - v0);
        const float w0 = 1.f / (1.f + tt);
        const float w1 = tt / (1.f + tt);
        sel[token * 2 + 0] = i0;  wts[token * 2 + 0] = w0;
        sel[token * 2 + 1] = i1;  wts[token * 2 + 1] = w1;
      }
    }
  } else {
    // ---------------- We-transpose part: [E][D][H] fp32 -> [E][H][D] bf16 ----------
    const int b = bi - NTOK / 16;
    if (b == 0 && tid < 64) counts[tid] = 0;   // route's counts, ready next node
    const int e = b >> 7;
    const int rem = b & 127;
    const int h0 = (rem & 15) * 64;
    const int d0 = (rem >> 4) * 128;
    float (*t)[65] = (float(*)[65])smem;

    {
      const int hc = (tid & 15) * 4;
      const float* src = We + ((size_t)e * DDIM + d0) * HDIM + h0 + hc;
#pragma unroll
      for (int i = 0; i < 8; ++i) {
        const int dr = (tid >> 4) + i * 16;
        const float4 v = *(const float4*)(src + (size_t)dr * HDIM);
        t[dr][hc] = v.x; t[dr][hc + 1] = v.y; t[dr][hc + 2] = v.z; t[dr][hc + 3] = v.w;
      }
    }
    __syncthreads();
    {
      const int dc = (tid & 7) * 16;
#pragma unroll
      for (int i2 = 0; i2 < 2; ++i2) {
        const int hr = (tid >> 3) + i2 * 32;
        us8 o0, o1;
#pragma unroll
        for (int j = 0; j < 8; ++j) ((unsigned short*)&o0)[j] = f2bf(t[dc + j][hr]);
#pragma unroll
        for (int j = 0; j < 8; ++j) ((unsigned short*)&o1)[j] = f2bf(t[dc + 8 + j][hr]);
        unsigned short* dst = wbt + ((size_t)e * HDIM + h0 + hr) * DDIM + d0 + dc;
        *(us8*)dst = o0;
        *(us8*)(dst + 8) = o1;
      }
    }
  }
}

// ---------------- route: block-aggregated scatter into per-expert lists -------------
__global__ __launch_bounds__(256) void route_kernel(
    const int* __restrict__ sel, const float* __restrict__ wts,
    int* __restrict__ counts, int* __restrict__ tlist, float* __restrict__ wlist,
    int* __restrict__ dstrow)
{
  __shared__ int bin[NEXP];
  __shared__ int base[NEXP];
  const int tid = threadIdx.x;
  if (tid < NEXP) bin[tid] = 0;
  __syncthreads();
  const int idx = blockIdx.x * 256 + tid;
  const int e = sel[idx];
  const float w = wts[idx];
  const int rank = atomicAdd(&bin[e], 1);
  __syncthreads();
  if (tid < NEXP) base[tid] = atomicAdd(&counts[tid], bin[tid]);
  __syncthreads();
  const int pos = base[e] + rank;
  tlist[e * NTOK + pos] = idx >> 1;
  wlist[e * NTOK + pos] = w;
  dstrow[e * NTOK + pos] = idx;
}

// ------- grouped GEMM (R3-verbatim + ebase): 256x128 tile, 8 waves, fp16 partials ---
__global__ __launch_bounds__(512, 4) void moe_gemm(
    const unsigned short* __restrict__ xb,
    const unsigned short* __restrict__ wbt,
    const float* __restrict__ be,
    const int* __restrict__ counts,
    const int* __restrict__ tlist,
    const float* __restrict__ wlist,
    const int* __restrict__ dstrow,
    __half* __restrict__ yb, const int ebase)
{
  const int e = blockIdx.z + ebase;
  const int cnt = counts[e];
  const int tile = blockIdx.y;
  if (tile * 256 >= cnt) return;
  const int n0 = blockIdx.x * 128;

  __shared__ unsigned short As[256 * 64];   // 32 KB
  __shared__ unsigned short Bs[128 * 64];   // 16 KB

  const int tid = threadIdx.x;              // 0..511
  const int lane = tid & 63;
  const int wv = tid >> 6;                  // 0..7
  const int wm = wv >> 1;                   // 0..3
  const int wn = wv & 1;                    // 0..1

  const int rA = tid >> 3;                  // 0..63
  const int kbA = (tid & 7) << 4;
  const unsigned short* aSrc[4];
  const unsigned short* bSrc[2];
  int ldsA[4]; int ldsB[2];
#pragma unroll
  for (int q = 0; q < 4; ++q) {
    const int r = q * 64 + rA;              // 0..255
    int trow = tile * 256 + r;
    trow = trow < cnt ? trow : cnt - 1;
    const int tok = tlist[e * NTOK + trow];
    const int kbs = kbA ^ ((r & 7) << 4);
    aSrc[q] = xb + (size_t)tok * DDIM + (kbs >> 1);
    ldsA[q] = r * 64 + (kbA >> 1);
  }
#pragma unroll
  for (int q = 0; q < 2; ++q) {
    const int r = q * 64 + rA;              // 0..127
    const int kbs = kbA ^ ((r & 7) << 4);
    bSrc[q] = wbt + ((size_t)e * HDIM + n0 + r) * DDIM + (kbs >> 1);
    ldsB[q] = r * 64 + (kbA >> 1);
  }

  f32x4 acc[4][4];
#pragma unroll
  for (int m = 0; m < 4; ++m)
#pragma unroll
    for (int n = 0; n < 4; ++n)
      acc[m][n] = (f32x4){0.f, 0.f, 0.f, 0.f};

  for (int kt = 0; kt < DDIM / 64; ++kt) {
    __syncthreads();
#pragma unroll
    for (int q = 0; q < 4; ++q) gload16(aSrc[q] + kt * 64, &As[ldsA[q]]);
#pragma unroll
    for (int q = 0; q < 2; ++q) gload16(bSrc[q] + kt * 64, &Bs[ldsB[q]]);
    __syncthreads();

#pragma unroll
    for (int kk = 0; kk < 2; ++kk) {
      const int kb = kk * 64 + ((lane >> 4) << 4);
      short8 af[4], bfr[4];
#pragma unroll
      for (int m = 0; m < 4; ++m) {
        const int r = wm * 64 + m * 16 + (lane & 15);
        af[m] = *(const short8*)((const char*)As + r * 128 + (kb ^ ((r & 7) << 4)));
      }
#pragma unroll
      for (int n = 0; n < 4; ++n) {
        const int r = wn * 64 + n * 16 + (lane & 15);
        bfr[n] = *(const short8*)((const char*)Bs + r * 128 + (kb ^ ((r & 7) << 4)));
      }
#pragma unroll
      for (int m = 0; m < 4; ++m)
#pragma unroll
        for (int n = 0; n < 4; ++n)
          acc[m][n] = __builtin_amdgcn_mfma_f32_16x16x32_bf16(af[m], bfr[n], acc[m][n], 0, 0, 0);
    }
  }

  const int rbase = wm * 64 + ((lane >> 4) << 2);
  const int cb = lane & 15;
  float bev[4];
#pragma unroll
  for (int n = 0; n < 4; ++n) bev[n] = be[e * HDIM + n0 + wn * 64 + n * 16 + cb];
#pragma unroll
  for (int m = 0; m < 4; ++m) {
#pragma unroll
    for (int r4 = 0; r4 < 4; ++r4) {
      const int trow = tile * 256 + rbase + m * 16 + r4;
      if (trow < cnt) {
        const int drow = dstrow[e * NTOK + trow];
        const float w = wlist[e * NTOK + trow];
        __half* yrow = yb + (size_t)drow * HDIM + n0 + wn * 64 + cb;
#pragma unroll
        for (int n = 0; n < 4; ++n)
          yrow[n * 16] = __float2half(w * (acc[m][n][r4] + bev[n]));
      }
    }
  }
}

// ---------------- combine: out[tok] = partial[tok*2] + partial[tok*2+1] -------------
__global__ __launch_bounds__(256) void combine_kernel(
    const __half* __restrict__ yb, float* __restrict__ out)
{
  const int g = blockIdx.x * 256 + threadIdx.x;
  const int tok = g >> 7;
  const int h0 = (g & 127) * 8;
  const short8 p0 = *(const short8*)(yb + ((size_t)tok * 2) * HDIM + h0);
  const short8 p1 = *(const short8*)(yb + ((size_t)tok * 2 + 1) * HDIM + h0);
  float r[8];
#pragma unroll
  for (int j = 0; j < 8; ++j) {
    __half a = *(const __half*)&((const short*)&p0)[j];
    __half b = *(const __half*)&((const short*)&p1)[j];
    r[j] = __half2float(a) + __half2float(b);
  }
  float* o = out + (size_t)tok * HDIM + h0;
  *(float4*)o = (float4){r[0], r[1], r[2], r[3]};
  *(float4*)(o + 4) = (float4){r[4], r[5], r[6], r[7]};
}

extern "C" void kernel_launch(void* const* d_in, const int* in_sizes, int n_in,
                              void* d_out, int out_size, void* d_ws, size_t ws_size,
                              hipStream_t stream)
{
  const float* x  = (const float*)d_in[0];
  const float* Wg = (const float*)d_in[1];
  const float* bg = (const float*)d_in[2];
  const float* We = (const float*)d_in[3];
  const float* be = (const float*)d_in[4];

  char* ws = (char*)d_ws;
  int*   counts = (int*)ws;                                   // 256 B
  int*   tlist  = (int*)(ws + 256);                           // 256 KB
  float* wlist  = (float*)(ws + 256 + NEXP * NTOK * 4);       // 256 KB
  int*   dstrow = (int*)(ws + 256 + 2 * NEXP * NTOK * 4);     // 256 KB
  int*   sel    = (int*)(ws + 256 + 3 * NEXP * NTOK * 4);     // 64 KB
  float* wts    = (float*)(ws + 256 + 3 * NEXP * NTOK * 4 + 2 * NTOK * 4); // 64 KB
  unsigned short* xb  = (unsigned short*)(ws + (1 << 21));                           // 16 MB
  unsigned short* wbt = (unsigned short*)(ws + (1 << 21) + (size_t)NTOK * DDIM * 2); // 16 MB
  __half* yb = (__half*)(ws + (1 << 21) + 2 * (size_t)NTOK * DDIM * 2);              // 32 MB
  float* out = (float*)d_out;

  // node 1: prep = gate (512 blocks) + We-transpose (1024 blocks) + counts zeroing
  prep_kernel<<<NTOK / 16 + NEXP * 128, 256, 0, stream>>>(
      x, Wg, bg, xb, sel, wts, We, wbt, counts);
  // node 2: route
  route_kernel<<<2 * NTOK / 256, 256, 0, stream>>>(sel, wts, counts, tlist, wlist, dstrow);
  // nodes 3+4: gemm split by expert halves (adjacent dispatches of one replay
  // surface in top-5 -> their timestamp gap measures per-node overhead directly)
  moe_gemm<<<dim3(HDIM / 128, NTOK / 256, NEXP / 2), 512, 0, stream>>>(
      xb, wbt, be, counts, tlist, wlist, dstrow, yb, 0);
  moe_gemm<<<dim3(HDIM / 128, NTOK / 256, NEXP / 2), 512, 0, stream>>>(
      xb, wbt, be, counts, tlist, wlist, dstrow, yb, NEXP / 2);
  // node 5: combine
  combine_kernel<<<NTOK * HDIM / 8 / 256, 256, 0, stream>>>(yb, out);
}

// Round 9
// 191.481 us; speedup vs baseline: 1.2817x; 1.0378x over previous
//
#include <hip/hip_runtime.h>
#include <hip/hip_bf16.h>
#include <hip/hip_fp16.h>

#define NTOK 8192
#define DDIM 1024
#define HDIM 1024
#define NEXP 8

typedef __attribute__((ext_vector_type(8))) short short8;
typedef __attribute__((ext_vector_type(4))) float f32x4;
typedef __attribute__((ext_vector_type(4))) unsigned short us4;
typedef __attribute__((ext_vector_type(8))) unsigned short us8;

static __device__ __forceinline__ unsigned short f2bf(float f) {
  union { float f; unsigned u; } v; v.f = f;
  return (unsigned short)((v.u + 0x7fffu + ((v.u >> 16) & 1u)) >> 16);
}

static __device__ __forceinline__ void gload16(const void* g, void* l) {
  __builtin_amdgcn_global_load_lds(
      (const __attribute__((address_space(1))) unsigned int*)g,
      (__attribute__((address_space(3))) unsigned int*)l, 16, 0, 0);
}

// ==== prep: blocks [0,512) = gate (Wg transposed in-LDS); [512,1536) = We-transpose;
//      We-block 0 additionally zeroes counts (consumed by route, next node). ====
__global__ __launch_bounds__(256) void prep_kernel(
    const float* __restrict__ x, const float* __restrict__ Wg,
    const float* __restrict__ bg, unsigned short* __restrict__ xb,
    int* __restrict__ sel, float* __restrict__ wts,
    const float* __restrict__ We, unsigned short* __restrict__ wbt,
    int* __restrict__ counts)
{
  __shared__ float smem[128 * 65];   // 33280 B, shared by both branches
  const int bi = blockIdx.x;
  const int tid = threadIdx.x;

  if (bi < NTOK / 16) {
    // ---------------- gate part: 16 tokens/block ----------------
    float* wg = smem;                // [NEXP][DDIM], 32 KB
#pragma unroll
    for (int k = 0; k < 4; ++k) {
      const int d = tid + k * 256;
      const float4 a = *(const float4*)(Wg + d * NEXP);
      const float4 b = *(const float4*)(Wg + d * NEXP + 4);
      wg[0 * DDIM + d] = a.x; wg[1 * DDIM + d] = a.y;
      wg[2 * DDIM + d] = a.z; wg[3 * DDIM + d] = a.w;
      wg[4 * DDIM + d] = b.x; wg[5 * DDIM + d] = b.y;
      wg[6 * DDIM + d] = b.z; wg[7 * DDIM + d] = b.w;
    }
    __syncthreads();

    const int wave = tid >> 6;
    const int lane = tid & 63;

    for (int t = 0; t < 4; ++t) {
      const int token = bi * 16 + wave * 4 + t;
      const float* xr = x + (size_t)token * DDIM;

      float acc[NEXP];
#pragma unroll
      for (int e = 0; e < NEXP; ++e) acc[e] = 0.f;

#pragma unroll
      for (int q = 0; q < 4; ++q) {
        const int d0 = q * 256 + lane * 4;
        const float4 xv = *(const float4*)(xr + d0);
        us4 hb;
        hb.x = f2bf(xv.x); hb.y = f2bf(xv.y); hb.z = f2bf(xv.z); hb.w = f2bf(xv.w);
        *(us4*)(xb + (size_t)token * DDIM + d0) = hb;
#pragma unroll
        for (int e = 0; e < NEXP; ++e) {
          const float4 wv = *(const float4*)&wg[e * DDIM + d0];
          acc[e] += xv.x * wv.x;   // same j-order as all previous passing kernels
          acc[e] += xv.y * wv.y;
          acc[e] += xv.z * wv.z;
          acc[e] += xv.w * wv.w;
        }
      }

#pragma unroll
      for (int e = 0; e < NEXP; ++e) {
#pragma unroll
        for (int off = 32; off >= 1; off >>= 1)
          acc[e] += __shfl_xor(acc[e], off, 64);
      }

      if (lane == 0) {
        float v[NEXP];
#pragma unroll
        for (int e = 0; e < NEXP; ++e) v[e] = acc[e] + bg[e];
        int i0 = 0; float v0 = v[0];
#pragma unroll
        for (int e = 1; e < NEXP; ++e) if (v[e] > v0) { v0 = v[e]; i0 = e; }
        int i1 = -1; float v1 = -3.4e38f;
#pragma unroll
        for (int e = 0; e < NEXP; ++e) if (e != i0 && v[e] > v1) { v1 = v[e]; i1 = e; }
        const float tt = __expf(v1 - v0);
        const float w0 = 1.f / (1.f + tt);
        const float w1 = tt / (1.f + tt);
        sel[token * 2 + 0] = i0;  wts[token * 2 + 0] = w0;
        sel[token * 2 + 1] = i1;  wts[token * 2 + 1] = w1;
      }
    }
  } else {
    // ---------------- We-transpose part: [E][D][H] fp32 -> [E][H][D] bf16 ----------
    const int b = bi - NTOK / 16;
    if (b == 0 && tid < 64) counts[tid] = 0;   // route's counts, ready next node
    const int e = b >> 7;
    const int rem = b & 127;
    const int h0 = (rem & 15) * 64;
    const int d0 = (rem >> 4) * 128;
    float (*t)[65] = (float(*)[65])smem;

    {
      const int hc = (tid & 15) * 4;
      const float* src = We + ((size_t)e * DDIM + d0) * HDIM + h0 + hc;
#pragma unroll
      for (int i = 0; i < 8; ++i) {
        const int dr = (tid >> 4) + i * 16;
        const float4 v = *(const float4*)(src + (size_t)dr * HDIM);
        t[dr][hc] = v.x; t[dr][hc + 1] = v.y; t[dr][hc + 2] = v.z; t[dr][hc + 3] = v.w;
      }
    }
    __syncthreads();
    {
      const int dc = (tid & 7) * 16;
#pragma unroll
      for (int i2 = 0; i2 < 2; ++i2) {
        const int hr = (tid >> 3) + i2 * 32;
        us8 o0, o1;
#pragma unroll
        for (int j = 0; j < 8; ++j) ((unsigned short*)&o0)[j] = f2bf(t[dc + j][hr]);
#pragma unroll
        for (int j = 0; j < 8; ++j) ((unsigned short*)&o1)[j] = f2bf(t[dc + 8 + j][hr]);
        unsigned short* dst = wbt + ((size_t)e * HDIM + h0 + hr) * DDIM + d0 + dc;
        *(us8*)dst = o0;
        *(us8*)(dst + 8) = o1;
      }
    }
  }
}

// ---------------- route: block-aggregated scatter into per-expert lists -------------
__global__ __launch_bounds__(256) void route_kernel(
    const int* __restrict__ sel, const float* __restrict__ wts,
    int* __restrict__ counts, int* __restrict__ tlist, float* __restrict__ wlist,
    int* __restrict__ dstrow)
{
  __shared__ int bin[NEXP];
  __shared__ int base[NEXP];
  const int tid = threadIdx.x;
  if (tid < NEXP) bin[tid] = 0;
  __syncthreads();
  const int idx = blockIdx.x * 256 + tid;
  const int e = sel[idx];
  const float w = wts[idx];
  const int rank = atomicAdd(&bin[e], 1);
  __syncthreads();
  if (tid < NEXP) base[tid] = atomicAdd(&counts[tid], bin[tid]);
  __syncthreads();
  const int pos = base[e] + rank;
  tlist[e * NTOK + pos] = idx >> 1;
  wlist[e * NTOK + pos] = w;
  dstrow[e * NTOK + pos] = idx;
}

// ------- grouped GEMM (R3-verbatim): 256x128 tile, BK=64, 8 waves, fp16 partials ----
__global__ __launch_bounds__(512, 4) void moe_gemm(
    const unsigned short* __restrict__ xb,
    const unsigned short* __restrict__ wbt,
    const float* __restrict__ be,
    const int* __restrict__ counts,
    const int* __restrict__ tlist,
    const float* __restrict__ wlist,
    const int* __restrict__ dstrow,
    __half* __restrict__ yb)
{
  const int e = blockIdx.z;
  const int cnt = counts[e];
  const int tile = blockIdx.y;
  if (tile * 256 >= cnt) return;
  const int n0 = blockIdx.x * 128;

  __shared__ unsigned short As[256 * 64];   // 32 KB
  __shared__ unsigned short Bs[128 * 64];   // 16 KB

  const int tid = threadIdx.x;              // 0..511
  const int lane = tid & 63;
  const int wv = tid >> 6;                  // 0..7
  const int wm = wv >> 1;                   // 0..3
  const int wn = wv & 1;                    // 0..1

  const int rA = tid >> 3;                  // 0..63
  const int kbA = (tid & 7) << 4;
  const unsigned short* aSrc[4];
  const unsigned short* bSrc[2];
  int ldsA[4]; int ldsB[2];
#pragma unroll
  for (int q = 0; q < 4; ++q) {
    const int r = q * 64 + rA;              // 0..255
    int trow = tile * 256 + r;
    trow = trow < cnt ? trow : cnt - 1;
    const int tok = tlist[e * NTOK + trow];
    const int kbs = kbA ^ ((r & 7) << 4);
    aSrc[q] = xb + (size_t)tok * DDIM + (kbs >> 1);
    ldsA[q] = r * 64 + (kbA >> 1);
  }
#pragma unroll
  for (int q = 0; q < 2; ++q) {
    const int r = q * 64 + rA;              // 0..127
    const int kbs = kbA ^ ((r & 7) << 4);
    bSrc[q] = wbt + ((size_t)e * HDIM + n0 + r) * DDIM + (kbs >> 1);
    ldsB[q] = r * 64 + (kbA >> 1);
  }

  f32x4 acc[4][4];
#pragma unroll
  for (int m = 0; m < 4; ++m)
#pragma unroll
    for (int n = 0; n < 4; ++n)
      acc[m][n] = (f32x4){0.f, 0.f, 0.f, 0.f};

  for (int kt = 0; kt < DDIM / 64; ++kt) {
    __syncthreads();
#pragma unroll
    for (int q = 0; q < 4; ++q) gload16(aSrc[q] + kt * 64, &As[ldsA[q]]);
#pragma unroll
    for (int q = 0; q < 2; ++q) gload16(bSrc[q] + kt * 64, &Bs[ldsB[q]]);
    __syncthreads();

#pragma unroll
    for (int kk = 0; kk < 2; ++kk) {
      const int kb = kk * 64 + ((lane >> 4) << 4);
      short8 af[4], bfr[4];
#pragma unroll
      for (int m = 0; m < 4; ++m) {
        const int r = wm * 64 + m * 16 + (lane & 15);
        af[m] = *(const short8*)((const char*)As + r * 128 + (kb ^ ((r & 7) << 4)));
      }
#pragma unroll
      for (int n = 0; n < 4; ++n) {
        const int r = wn * 64 + n * 16 + (lane & 15);
        bfr[n] = *(const short8*)((const char*)Bs + r * 128 + (kb ^ ((r & 7) << 4)));
      }
#pragma unroll
      for (int m = 0; m < 4; ++m)
#pragma unroll
        for (int n = 0; n < 4; ++n)
          acc[m][n] = __builtin_amdgcn_mfma_f32_16x16x32_bf16(af[m], bfr[n], acc[m][n], 0, 0, 0);
    }
  }

  const int rbase = wm * 64 + ((lane >> 4) << 2);
  const int cb = lane & 15;
  float bev[4];
#pragma unroll
  for (int n = 0; n < 4; ++n) bev[n] = be[e * HDIM + n0 + wn * 64 + n * 16 + cb];
#pragma unroll
  for (int m = 0; m < 4; ++m) {
#pragma unroll
    for (int r4 = 0; r4 < 4; ++r4) {
      const int trow = tile * 256 + rbase + m * 16 + r4;
      if (trow < cnt) {
        const int drow = dstrow[e * NTOK + trow];
        const float w = wlist[e * NTOK + trow];
        __half* yrow = yb + (size_t)drow * HDIM + n0 + wn * 64 + cb;
#pragma unroll
        for (int n = 0; n < 4; ++n)
          yrow[n * 16] = __float2half(w * (acc[m][n][r4] + bev[n]));
      }
    }
  }
}

// ---------------- combine: out[tok] = partial[tok*2] + partial[tok*2+1] -------------
__global__ __launch_bounds__(256) void combine_kernel(
    const __half* __restrict__ yb, float* __restrict__ out)
{
  const int g = blockIdx.x * 256 + threadIdx.x;
  const int tok = g >> 7;
  const int h0 = (g & 127) * 8;
  const short8 p0 = *(const short8*)(yb + ((size_t)tok * 2) * HDIM + h0);
  const short8 p1 = *(const short8*)(yb + ((size_t)tok * 2 + 1) * HDIM + h0);
  float r[8];
#pragma unroll
  for (int j = 0; j < 8; ++j) {
    __half a = *(const __half*)&((const short*)&p0)[j];
    __half b = *(const __half*)&((const short*)&p1)[j];
    r[j] = __half2float(a) + __half2float(b);
  }
  float* o = out + (size_t)tok * HDIM + h0;
  *(float4*)o = (float4){r[0], r[1], r[2], r[3]};
  *(float4*)(o + 4) = (float4){r[4], r[5], r[6], r[7]};
}

extern "C" void kernel_launch(void* const* d_in, const int* in_sizes, int n_in,
                              void* d_out, int out_size, void* d_ws, size_t ws_size,
                              hipStream_t stream)
{
  const float* x  = (const float*)d_in[0];
  const float* Wg = (const float*)d_in[1];
  const float* bg = (const float*)d_in[2];
  const float* We = (const float*)d_in[3];
  const float* be = (const float*)d_in[4];

  char* ws = (char*)d_ws;
  int*   counts = (int*)ws;                                   // 256 B
  int*   tlist  = (int*)(ws + 256);                           // 256 KB
  float* wlist  = (float*)(ws + 256 + NEXP * NTOK * 4);       // 256 KB
  int*   dstrow = (int*)(ws + 256 + 2 * NEXP * NTOK * 4);     // 256 KB
  int*   sel    = (int*)(ws + 256 + 3 * NEXP * NTOK * 4);     // 64 KB
  float* wts    = (float*)(ws + 256 + 3 * NEXP * NTOK * 4 + 2 * NTOK * 4); // 64 KB
  unsigned short* xb  = (unsigned short*)(ws + (1 << 21));                           // 16 MB
  unsigned short* wbt = (unsigned short*)(ws + (1 << 21) + (size_t)NTOK * DDIM * 2); // 16 MB
  __half* yb = (__half*)(ws + (1 << 21) + 2 * (size_t)NTOK * DDIM * 2);              // 32 MB
  float* out = (float*)d_out;

  // node 1: prep = gate (512 blocks) + We-transpose (1024 blocks) + counts zeroing
  prep_kernel<<<NTOK / 16 + NEXP * 128, 256, 0, stream>>>(
      x, Wg, bg, xb, sel, wts, We, wbt, counts);
  // node 2: route
  route_kernel<<<2 * NTOK / 256, 256, 0, stream>>>(sel, wts, counts, tlist, wlist, dstrow);
  // node 3: unified grouped GEMM (512 useful blocks -> 2/CU co-residency)
  moe_gemm<<<dim3(HDIM / 128, NTOK / 256, NEXP), 512, 0, stream>>>(
      xb, wbt, be, counts, tlist, wlist, dstrow, yb);
  // node 4: combine
  combine_kernel<<<NTOK * HDIM / 8 / 256, 256, 0, stream>>>(yb, out);
}